// Round 7
// baseline (183.745 us; speedup 1.0000x reference)
//
#include <hip/hip_runtime.h>
#include <math.h>

// Problem constants: B=16, C_in=256, H=W=32 -> N=1024, qkv_out=1536,
// HEAD=8, dh=dv=64, V_DIM=512, OUT_CH=256.
static constexpr int Bsz = 16;
static constexpr int Np  = 1024;
static constexpr int Cin = 256;

typedef __attribute__((ext_vector_type(8))) short short8;  // 8 bf16 = 4 VGPR
typedef __attribute__((ext_vector_type(4))) float f4;      // mfma acc

// v_exp_f32 computes 2^x natively; use it without the log2e multiply.
#if defined(__has_builtin)
#if __has_builtin(__builtin_amdgcn_exp2f)
#define EXP2(x) __builtin_amdgcn_exp2f(x)
#else
#define EXP2(x) exp2f(x)
#endif
#else
#define EXP2(x) exp2f(x)
#endif

// q pre-scale: dh^-0.5 * log2(e), folded in fp32 BEFORE the single bf16
// rounding (scores exit QK^T already in log2 domain)
#define QSCALE 0.18033688011112f

// fp32 -> bf16 round-to-nearest-even (scalar path, used by GEMM kernels)
__device__ __forceinline__ unsigned short f2b(float f) {
    union { float fp; unsigned int u; } v; v.fp = f;
    unsigned int r = v.u + 0x7fffu + ((v.u >> 16) & 1u);
    return (unsigned short)(r >> 16);
}

// two fp32 -> packed 2x bf16 (RNE), lo = a, hi = b
__device__ __forceinline__ unsigned cvtpk(float a, float b) {
    unsigned r;
    asm("v_cvt_pk_bf16_f32 %0, %1, %2" : "=v"(r) : "v"(a), "v"(b));
    return r;
}

// XOR-swizzled LDS addressing for 64-col (128 B) bf16 rows (stride 64, NO
// pad): byte = (row*128 + col*2) ^ ((row&7)<<4). Bijective within each 8-row
// stripe; measured conflict-free for the b128 fragment-read pattern (r1 vs r2
// counters). Writes of 8/16 B stay slot-contained (XOR touches bits 4-6 only).
// global_load_lds writes LINEAR LDS with the same XOR folded into the
// per-lane global SOURCE address (m201 pattern).
__device__ __forceinline__ void* swzp(const void* base, int row, int col) {
    return (void*)((const char*)base + ((row * 128 + col * 2) ^ ((row & 7) << 4)));
}

// async global->LDS, 16 B per lane; dest = wave-uniform base + lane*16.
__device__ __forceinline__ void gl16(const ushort* g, ushort* l) {
    __builtin_amdgcn_global_load_lds(
        (const __attribute__((address_space(1))) unsigned int*)g,
        (__attribute__((address_space(3))) unsigned int*)l, 16, 0, 0);
}

// ---------------------------------------------------------------------------
// Kernel 0: cast+transpose x [b][c][n] fp32 -> xb [b][n][c] bf16 (y<4),
// and cast qkv_w / proj_w fp32 -> bf16 (y==4). Single launch.
// ---------------------------------------------------------------------------
__global__ __launch_bounds__(256)
void cast_xw(const float* __restrict__ x, const float* __restrict__ qw,
             const float* __restrict__ pw, ushort* __restrict__ xb,
             ushort* __restrict__ qwb, ushort* __restrict__ pwb)
{
    const int t = threadIdx.x;
    if (blockIdx.y < 4) {
        __shared__ ushort T[64][72];   // [n][c]
        const int n0 = blockIdx.x * 64, c0 = blockIdx.y * 64, b = blockIdx.z;
        {   // read 64c x 64n, convert, transposed scatter into LDS
            const int c_l = t >> 2, ns = (t & 3) * 16;
            const float* src = &x[((b * Cin + c0 + c_l) << 10) + n0 + ns];
#pragma unroll
            for (int i = 0; i < 4; ++i) {
                const float4 v = *(const float4*)(src + 4 * i);
                T[ns + 4 * i + 0][c_l] = f2b(v.x);
                T[ns + 4 * i + 1][c_l] = f2b(v.y);
                T[ns + 4 * i + 2][c_l] = f2b(v.z);
                T[ns + 4 * i + 3][c_l] = f2b(v.w);
            }
        }
        __syncthreads();
        {   // write rows of c (contiguous) to xb
            const int n_l = t >> 2, cs = (t & 3) * 16;
            ushort* dst = &xb[((b << 10) + n0 + n_l) * Cin + c0 + cs];
            *(uint4*)dst       = *(const uint4*)&T[n_l][cs];
            *(uint4*)(dst + 8) = *(const uint4*)&T[n_l][cs + 8];
        }
    } else {
        // weights: 524288 floats total = 131072 float4; 256 blocks x 256 thr x 2
        const int nq4 = (1536 * Cin) / 4;
        const int base = ((blockIdx.z * 16 + blockIdx.x) * 256 + t) * 2;
#pragma unroll
        for (int g = 0; g < 2; ++g) {
            const int j = base + g;
            const float* src; ushort* dst; int jj;
            if (j < nq4) { src = qw; dst = qwb; jj = j; }
            else         { src = pw; dst = pwb; jj = j - nq4; }
            const float4 v = *(const float4*)(src + 4 * jj);
            ushort4 u; u.x = f2b(v.x); u.y = f2b(v.y); u.z = f2b(v.z); u.w = f2b(v.w);
            *(ushort4*)(dst + 4 * jj) = u;
        }
    }
}

// ---------------------------------------------------------------------------
// Kernel 1: QKV GEMM (unchanged from r5), bf16 MFMA 16x16x32, BK=64,
// global_load_lds staging into linear LDS + source-side XOR swizzle.
// ---------------------------------------------------------------------------
__global__ __launch_bounds__(256)
void qkv_gemm(const ushort* __restrict__ xb, const ushort* __restrict__ wb,
              const float* __restrict__ bias,
              ushort* __restrict__ qb, ushort* __restrict__ kb, ushort* __restrict__ vb)
{
    __shared__ ushort lds[17408];        // 34.8 KB; staging (32 KB) + Ct alias
    ushort* As = lds;                    // [128 o][64]  (linear, swizzled data)
    ushort* Bs = lds + 8192;             // [128 n][64]

    const int t = threadIdx.x;
    const int w = t >> 6, lane = t & 63, quad = lane >> 4, ln = lane & 15;
    const int n0 = blockIdx.x * 128;
    const int o0 = blockIdx.y * 128;
    const int b  = blockIdx.z;
    const int ow = (w & 1) * 64, nw = (w >> 1) * 64;
    const bool vpath = (o0 >= 1024);

    const int r8  = lane >> 3;
    const int c16 = ((lane & 7) ^ r8) << 3;

    f4 acc[4][4];
#pragma unroll
    for (int i = 0; i < 4; ++i)
#pragma unroll
        for (int j = 0; j < 4; ++j) acc[i][j] = (f4){0.f, 0.f, 0.f, 0.f};

    for (int k0 = 0; k0 < Cin; k0 += 64) {
        __syncthreads();
#pragma unroll
        for (int j = 0; j < 4; ++j) {    // wave w stages rows [w*32, w*32+32)
            const int row = w * 32 + j * 8 + r8;
            gl16(&wb[(o0 + row) * Cin + k0 + c16],              &As[(w * 32 + j * 8) * 64]);
            gl16(&xb[((b << 10) + n0 + row) * Cin + k0 + c16],  &Bs[(w * 32 + j * 8) * 64]);
        }
        __syncthreads();                 // drains vmcnt -> tile visible
#pragma unroll
        for (int sub = 0; sub < 2; ++sub) {
            short8 af[4], bf[4];
#pragma unroll
            for (int ot = 0; ot < 4; ++ot)
                af[ot] = *(const short8*)swzp(As, ow + ot * 16 + ln, sub * 32 + quad * 8);
#pragma unroll
            for (int nt = 0; nt < 4; ++nt)
                bf[nt] = *(const short8*)swzp(Bs, nw + nt * 16 + ln, sub * 32 + quad * 8);
            if (!vpath) {   // acc[ot][nt]: row = o, col = n
#pragma unroll
                for (int ot = 0; ot < 4; ++ot)
#pragma unroll
                    for (int nt = 0; nt < 4; ++nt)
                        acc[ot][nt] = __builtin_amdgcn_mfma_f32_16x16x32_bf16(
                            af[ot], bf[nt], acc[ot][nt], 0, 0, 0);
            } else {        // acc[nt][ot]: row = n, col = o (transposed C)
#pragma unroll
                for (int nt = 0; nt < 4; ++nt)
#pragma unroll
                    for (int ot = 0; ot < 4; ++ot)
                        acc[nt][ot] = __builtin_amdgcn_mfma_f32_16x16x32_bf16(
                            bf[nt], af[ot], acc[nt][ot], 0, 0, 0);
            }
        }
    }

    __syncthreads();                     // staging reads done; alias lds
    if (!vpath) {
        // ---- Q/K epilogue: Ct [n][136 o-stride], vectorized both ways ----
        ushort* Ct = lds;
        const float sc = (o0 < 512) ? QSCALE : 1.0f;
#pragma unroll
        for (int ot = 0; ot < 4; ++ot) {
            float bs[4];
#pragma unroll
            for (int rg = 0; rg < 4; ++rg)
                bs[rg] = bias[o0 + ow + ot * 16 + quad * 4 + rg];
#pragma unroll
            for (int nt = 0; nt < 4; ++nt) {
                ushort4 u;
                u.x = f2b((acc[ot][nt][0] + bs[0]) * sc);
                u.y = f2b((acc[ot][nt][1] + bs[1]) * sc);
                u.z = f2b((acc[ot][nt][2] + bs[2]) * sc);
                u.w = f2b((acc[ot][nt][3] + bs[3]) * sc);
                *(ushort4*)&Ct[(nw + nt * 16 + ln) * 136 + ow + ot * 16 + quad * 4] = u;
            }
        }
        __syncthreads();
        ushort* dst; int obase;
        if (o0 < 512) { dst = qb; obase = o0; }
        else          { dst = kb; obase = o0 - 512; }
        const int rn = t >> 1, hf = t & 1;
        const int bh = b * 8 + (obase >> 6) + hf;
        ushort* drow = &dst[(bh * Np + n0 + rn) << 6];
        const ushort* srow = &Ct[rn * 136 + hf * 64];
#pragma unroll
        for (int s = 0; s < 8; ++s)
            *(uint4*)(drow + s * 8) = *(const uint4*)(srow + s * 8);
    } else {
        // ---- V epilogue: Ct [o][136 n-stride] (rows = d), then [bh][d][n] ----
        ushort* Ct = lds;
#pragma unroll
        for (int ot = 0; ot < 4; ++ot) {
            const float bo = bias[o0 + ow + ot * 16 + ln];
#pragma unroll
            for (int nt = 0; nt < 4; ++nt) {
                ushort4 u;
                u.x = f2b(acc[nt][ot][0] + bo);
                u.y = f2b(acc[nt][ot][1] + bo);
                u.z = f2b(acc[nt][ot][2] + bo);
                u.w = f2b(acc[nt][ot][3] + bo);
                *(ushort4*)&Ct[(ow + ot * 16 + ln) * 136 + nw + nt * 16 + quad * 4] = u;
            }
        }
        __syncthreads();
        const int o_l = t >> 1, nh = (t & 1) * 64;
        const int bh = b * 8 + ((o0 - 1024) >> 6) + (o_l >> 6);
        ushort* drow = &vb[((size_t)bh << 16) + ((o_l & 63) << 10) + n0 + nh];
        const ushort* srow = &Ct[o_l * 136 + nh];
#pragma unroll
        for (int s = 0; s < 8; ++s)
            *(uint4*)(drow + s * 8) = *(const uint4*)(srow + s * 8);
    }
}

// ---------------------------------------------------------------------------
// Kernel 2: causal flash attention — 128 q-rows/block (2 q-frags per wave).
//  * LDS-BW analysis: K/V fragment reads are duplicated per wave, so doubling
//    q-rows per wave halves LDS traffic per unit work (per-step ~112 KB now
//    serves 2x the FLOPs; steps 17408 -> 9216; floor ~23 -> ~13 us/chip).
//  * r5-proven skeleton: plain __syncthreads, single-buffer gl16 staging
//    (linear LDS dest + source-side XOR swizzle), swzp fragment reads.
//  * r2-proven 2-frag loop body: dual per-lane softmax state (m0,l0,m1,l1),
//    absolute-index causal masks, O^T = mfma(V,P) per-lane state epilogue.
//  * Ps [128][64] XOR-swizzled (conflict-free, r6-validated). LDS 32 KB.
//  * Grid 1024 = 128 bh x 8 q-blocks, heavy-first; same-bh blocks 128 apart
//    -> same XCD -> K/V L2-local.
// ---------------------------------------------------------------------------
__global__ __launch_bounds__(256, 4)
void attn(const ushort* __restrict__ qb, const ushort* __restrict__ kb,
          const ushort* __restrict__ vt, ushort* __restrict__ ob)
{
    __shared__ ushort Ks[4096];      // [k][d], linear+swizzled data (8 KB)
    __shared__ ushort Vt[4096];      // [d][k], linear+swizzled data (8 KB)
    __shared__ ushort Ps[8192];      // [q_local][k], swizzled, wave-private rows

    const int t    = threadIdx.x;
    const int w    = t >> 6;
    const int lane = t & 63;
    const int quad = lane >> 4;
    const int ln   = lane & 15;
    const int bh   = blockIdx.x & 127;
    const int qbk  = 7 - (int)(blockIdx.x >> 7);   // heavy blocks first
    const int q0   = qbk * 128;

    const int base0 = q0 + w * 32;       // first q row of frag0
    const int qhi0  = base0 + 15;        // last q row of frag0
    const int qhi1  = base0 + 31;        // last q row of frag1

    const ushort* __restrict__ kbh = kb + ((size_t)(bh * Np) << 6);
    const ushort* __restrict__ vbh = vt + ((size_t)bh << 16);

    const int r8  = lane >> 3;                      // staging source mapping
    const int c16 = ((lane & 7) ^ r8) << 3;

    // Q fragments live in registers for the whole block (16 VGPR)
    short8 qa00, qa01, qa10, qa11;
    {
        const ushort* qr = &qb[((size_t)(bh * Np + base0 + ln) << 6) + quad * 8];
        qa00 = *(const short8*)qr;
        qa01 = *(const short8*)(qr + 32);
        qa10 = *(const short8*)(qr + 1024);        // +16 rows
        qa11 = *(const short8*)(qr + 1024 + 32);
    }

    f4 o0[4], o1[4];
#pragma unroll
    for (int nt = 0; nt < 4; ++nt) { o0[nt] = (f4){0.f,0.f,0.f,0.f}; o1[nt] = (f4){0.f,0.f,0.f,0.f}; }
    float m0 = -INFINITY, l0 = 0.f;      // state for q = base0 + ln
    float m1 = -INFINITY, l1 = 0.f;      // state for q = base0 + 16 + ln

    const int prow0 = w * 32 + ln;       // own wave's P rows
    const int prow1 = prow0 + 16;

    const int ktmax = 2 * qbk + 1;       // block-uniform loop bound
    for (int kt = 0; kt <= ktmax; ++kt) {
        const int k0 = kt * 64;
        __syncthreads();                 // all reads of previous tile done
#pragma unroll
        for (int j = 0; j < 2; ++j) {    // wave w stages K/V chunks 2w, 2w+1
            const int ch  = w * 2 + j;
            const int row = ch * 8 + r8;
            gl16(&kbh[((k0 + row) << 6) + c16],               &Ks[ch * 512]);
            gl16(&vbh[((size_t)row << 10) + k0 + c16],        &Vt[ch * 512]);
        }
        __syncthreads();                 // drains vmcnt -> tile visible

        if (k0 <= qhi1) {   // wave-uniform: this wave has unmasked keys
            // ---- S^T = K Q^T (shared K frags feed both q-frags), log2 domain
            f4 s0[4], s1[4];
#pragma unroll
            for (int mt = 0; mt < 4; ++mt) { s0[mt] = (f4){0.f,0.f,0.f,0.f}; s1[mt] = (f4){0.f,0.f,0.f,0.f}; }
#pragma unroll
            for (int mt = 0; mt < 4; ++mt) {
                const int kmt = k0 + mt * 16;
                if (kmt > qhi1) continue;             // fully masked for wave
                const short8 ka0 = *(const short8*)swzp(Ks, mt * 16 + ln, quad * 8);
                const short8 ka1 = *(const short8*)swzp(Ks, mt * 16 + ln, 32 + quad * 8);
                s1[mt] = __builtin_amdgcn_mfma_f32_16x16x32_bf16(ka0, qa10, s1[mt], 0, 0, 0);
                s1[mt] = __builtin_amdgcn_mfma_f32_16x16x32_bf16(ka1, qa11, s1[mt], 0, 0, 0);
                if (kmt <= qhi0) {
                    s0[mt] = __builtin_amdgcn_mfma_f32_16x16x32_bf16(ka0, qa00, s0[mt], 0, 0, 0);
                    s0[mt] = __builtin_amdgcn_mfma_f32_16x16x32_bf16(ka1, qa01, s0[mt], 0, 0, 0);
                }
            }

            // ---- causal mask (absolute indices), only near the diagonal
            if (k0 + 63 > base0) {
                const int q = base0 + ln;
#pragma unroll
                for (int mt = 0; mt < 4; ++mt)
#pragma unroll
                    for (int rg = 0; rg < 4; ++rg)
                        if (k0 + mt * 16 + quad * 4 + rg > q) s0[mt][rg] = -INFINITY;
            }
            if (k0 + 63 > base0 + 16) {
                const int q = base0 + 16 + ln;
#pragma unroll
                for (int mt = 0; mt < 4; ++mt)
#pragma unroll
                    for (int rg = 0; rg < 4; ++rg)
                        if (k0 + mt * 16 + quad * 4 + rg > q) s1[mt][rg] = -INFINITY;
            }

            // ---- online softmax frag0 (deferred rescale, THR=8, log2 domain)
            if (k0 <= qhi0) {
                float mx = s0[0][0];
#pragma unroll
                for (int mt = 0; mt < 4; ++mt)
#pragma unroll
                    for (int rg = 0; rg < 4; ++rg) mx = fmaxf(mx, s0[mt][rg]);
                mx = fmaxf(mx, __shfl_xor(mx, 16));
                mx = fmaxf(mx, __shfl_xor(mx, 32));
                if (!__all(mx <= m0 + 8.f)) {
                    const float mn = fmaxf(m0, mx);
                    const float al = EXP2(m0 - mn);   // first tile: exp2(-inf)=0
                    m0 = mn; l0 *= al;
#pragma unroll
                    for (int nt = 0; nt < 4; ++nt)
#pragma unroll
                        for (int rg = 0; rg < 4; ++rg) o0[nt][rg] *= al;
                }
                float rs = 0.f;
#pragma unroll
                for (int mt = 0; mt < 4; ++mt) {
                    const float p0 = EXP2(s0[mt][0] - m0);
                    const float p1 = EXP2(s0[mt][1] - m0);
                    const float p2 = EXP2(s0[mt][2] - m0);
                    const float p3 = EXP2(s0[mt][3] - m0);
                    rs += (p0 + p1) + (p2 + p3);
                    uint2 u; u.x = cvtpk(p0, p1); u.y = cvtpk(p2, p3);
                    *(uint2*)swzp(Ps, prow0, mt * 16 + quad * 4) = u;
                }
                rs += __shfl_xor(rs, 16);
                rs += __shfl_xor(rs, 32);
                l0 += rs;
            }
            // ---- frag1 (always has work when k0 <= qhi1)
            {
                float mx = s1[0][0];
#pragma unroll
                for (int mt = 0; mt < 4; ++mt)
#pragma unroll
                    for (int rg = 0; rg < 4; ++rg) mx = fmaxf(mx, s1[mt][rg]);
                mx = fmaxf(mx, __shfl_xor(mx, 16));
                mx = fmaxf(mx, __shfl_xor(mx, 32));
                if (!__all(mx <= m1 + 8.f)) {
                    const float mn = fmaxf(m1, mx);
                    const float al = EXP2(m1 - mn);
                    m1 = mn; l1 *= al;
#pragma unroll
                    for (int nt = 0; nt < 4; ++nt)
#pragma unroll
                        for (int rg = 0; rg < 4; ++rg) o1[nt][rg] *= al;
                }
                float rs = 0.f;
#pragma unroll
                for (int mt = 0; mt < 4; ++mt) {
                    const float p0 = EXP2(s1[mt][0] - m1);
                    const float p1 = EXP2(s1[mt][1] - m1);
                    const float p2 = EXP2(s1[mt][2] - m1);
                    const float p3 = EXP2(s1[mt][3] - m1);
                    rs += (p0 + p1) + (p2 + p3);
                    uint2 u; u.x = cvtpk(p0, p1); u.y = cvtpk(p2, p3);
                    *(uint2*)swzp(Ps, prow1, mt * 16 + quad * 4) = u;
                }
                rs += __shfl_xor(rs, 16);
                rs += __shfl_xor(rs, 32);
                l1 += rs;
            }

            // ---- O^T += V P : A = V frag (rows d), B = P frag (rows k).
            // V frags shared by both q-frags; output col = lane's own q row.
#pragma unroll
            for (int ks = 0; ks < 2; ++ks) {
                const int kk = k0 + ks * 32;
                if (kk > qhi1) continue;              // both P halves all-zero
                const short8 pa1 = *(const short8*)swzp(Ps, prow1, ks * 32 + quad * 8);
                const short8 pa0 = *(const short8*)swzp(Ps, prow0, ks * 32 + quad * 8);
                const bool do0 = (kk <= qhi0);
#pragma unroll
                for (int nt = 0; nt < 4; ++nt) {
                    const short8 vf = *(const short8*)swzp(Vt, nt * 16 + ln, ks * 32 + quad * 8);
                    o1[nt] = __builtin_amdgcn_mfma_f32_16x16x32_bf16(vf, pa1, o1[nt], 0, 0, 0);
                    if (do0)
                        o0[nt] = __builtin_amdgcn_mfma_f32_16x16x32_bf16(vf, pa0, o0[nt], 0, 0, 0);
                }
            }
        }
    }

    // ---- epilogue: O^T rows d = nt*16+quad*4+rg, col q = own lane's row.
    const float li0 = 1.0f / l0;
    const float li1 = 1.0f / l1;
    ushort* orow0 = &ob[(size_t)(bh * Np + base0 + ln) << 6];
    ushort* orow1 = orow0 + 1024;        // +16 q rows
#pragma unroll
    for (int nt = 0; nt < 4; ++nt) {
        uint2 u;
        u.x = cvtpk(o0[nt][0] * li0, o0[nt][1] * li0);
        u.y = cvtpk(o0[nt][2] * li0, o0[nt][3] * li0);
        *(uint2*)(orow0 + nt * 16 + quad * 4) = u;
        uint2 v;
        v.x = cvtpk(o1[nt][0] * li1, o1[nt][1] * li1);
        v.y = cvtpk(o1[nt][2] * li1, o1[nt][3] * li1);
        *(uint2*)(orow1 + nt * 16 + quad * 4) = v;
    }
}

// ---------------------------------------------------------------------------
// Kernel 3: projection GEMM (reverted to r5), bf16 MFMA, 64(o) x 128(n) tile,
// BK=64, global_load_lds staging. Grid 512 blocks; wave w owns n strip.
// ---------------------------------------------------------------------------
__global__ __launch_bounds__(256)
void proj_gemm(const ushort* __restrict__ obuf, const ushort* __restrict__ pwb,
               const float* __restrict__ bias, float* __restrict__ out)
{
    __shared__ ushort As[64 * 64];    // pw [o][k]        (8 KB)
    __shared__ ushort Bs[128 * 64];   // attn-out [n][k] (16 KB)

    const int t = threadIdx.x;
    const int w = t >> 6, lane = t & 63, quad = lane >> 4, ln = lane & 15;
    const int n0 = blockIdx.x * 128;
    const int o0 = blockIdx.y * 64;
    const int b  = blockIdx.z;
    const int nw = w * 32;

    const int r8  = lane >> 3;
    const int c16 = ((lane & 7) ^ r8) << 3;

    f4 acc[4][2];
#pragma unroll
    for (int i = 0; i < 4; ++i)
#pragma unroll
        for (int j = 0; j < 2; ++j) acc[i][j] = (f4){0.f, 0.f, 0.f, 0.f};

    for (int k0 = 0; k0 < 512; k0 += 64) {
        __syncthreads();
        {   // A: 8 chunks (wave w: 2w,2w+1); B: 16 chunks (wave w: 4w..4w+3)
            const int head = k0 >> 6;
#pragma unroll
            for (int j = 0; j < 2; ++j) {
                const int ch = w * 2 + j, row = ch * 8 + r8;
                gl16(&pwb[(o0 + row) * 512 + k0 + c16], &As[ch * 512]);
            }
#pragma unroll
            for (int j = 0; j < 4; ++j) {
                const int ch = w * 4 + j, row = ch * 8 + r8;
                gl16(&obuf[(((b * 8 + head) * Np + n0 + row) << 6) + c16], &Bs[ch * 512]);
            }
        }
        __syncthreads();                 // drains vmcnt -> tile visible
#pragma unroll
        for (int sub = 0; sub < 2; ++sub) {
            short8 af[4], bf[2];
#pragma unroll
            for (int ot = 0; ot < 4; ++ot)
                af[ot] = *(const short8*)swzp(As, ot * 16 + ln, sub * 32 + quad * 8);
#pragma unroll
            for (int nt = 0; nt < 2; ++nt)
                bf[nt] = *(const short8*)swzp(Bs, nw + nt * 16 + ln, sub * 32 + quad * 8);
#pragma unroll
            for (int ot = 0; ot < 4; ++ot)
#pragma unroll
                for (int nt = 0; nt < 2; ++nt)
                    acc[ot][nt] = __builtin_amdgcn_mfma_f32_16x16x32_bf16(
                        af[ot], bf[nt], acc[ot][nt], 0, 0, 0);
        }
    }

    // epilogue: direct fp32 stores (16-lane 64B segments), bias added
#pragma unroll
    for (int ot = 0; ot < 4; ++ot) {
#pragma unroll
        for (int rg = 0; rg < 4; ++rg) {
            const int oo = o0 + ot * 16 + quad * 4 + rg;
            const float pb = bias[oo];
            float* drow = &out[((b << 8) + oo) << 10];
#pragma unroll
            for (int nt = 0; nt < 2; ++nt)
                drow[n0 + nw + nt * 16 + ln] = acc[ot][nt][rg] + pb;
        }
    }
}

// ---------------------------------------------------------------------------
extern "C" void kernel_launch(void* const* d_in, const int* in_sizes, int n_in,
                              void* d_out, int out_size, void* d_ws, size_t ws_size,
                              hipStream_t stream)
{
    const float* x   = (const float*)d_in[0];   // [16,256,1024]
    const float* qw  = (const float*)d_in[1];   // [1536,256]
    const float* qbb = (const float*)d_in[2];   // [1536]
    const float* pw  = (const float*)d_in[3];   // [256,512]
    const float* pb  = (const float*)d_in[4];   // [256]
    float* out = (float*)d_out;                 // [16,256,1024]

    // workspace (all bf16): q/k [bh][n][64], v TRANSPOSED [bh][64][n],
    // attn-out [bh][n][64]; xb [b][n][c]; weights.
    const size_t per = (size_t)Bsz * 8 * Np * 64;
    ushort* qbuf = (ushort*)d_ws;
    ushort* kbuf = qbuf + per;
    ushort* vbuf = kbuf + per;
    ushort* obuf = vbuf + per;
    ushort* xb   = obuf + per;
    ushort* qwb  = xb + (size_t)Bsz * Np * Cin;
    ushort* pwb  = qwb + 1536 * Cin;

    cast_xw<<<dim3(16, 5, Bsz), 256, 0, stream>>>(x, qw, pw, xb, qwb, pwb);
    qkv_gemm<<<dim3(8, 12, Bsz), 256, 0, stream>>>(xb, qwb, qbb, qbuf, kbuf, vbuf);
    // 1024 blocks = 128 bh x 8 q-blocks of 128 rows; heavy (high qbk) first.
    // Same-bh blocks are 128 apart -> same XCD (128 % 8 == 0) -> K/V L2-local.
    attn<<<dim3(1024), 256, 0, stream>>>(qbuf, kbuf, vbuf, obuf);
    proj_gemm<<<dim3(8, 4, Bsz), 256, 0, stream>>>(obuf, pwb, pb, out);
}